// Round 5
// baseline (1089.260 us; speedup 1.0000x reference)
//
#include <hip/hip_runtime.h>
#include <hip/hip_bf16.h>

#define NN 8192
#define FIN 128
#define FOUT 64
#define ALPHA 0.2f
#define BM 64                // rows per attn block
#define CHUNK 128            // j-tile per pipeline stage
#define SPLIT 8              // j-range split factor (1024 j per block)
#define JSLICE (NN / SPLIT)
#define NCHUNK (JSLICE / CHUNK)
#define PROW (CHUNK + 8)     // 272B row stride: 4-bank skew
#define LOG2E 1.44269504f

typedef __attribute__((ext_vector_type(8))) short short8;   // 8 bf16 (4 VGPRs)
typedef __attribute__((ext_vector_type(4))) float floatx4;

#if __has_builtin(__builtin_amdgcn_exp2f)
#define EXP2(x) __builtin_amdgcn_exp2f(x)
#else
#define EXP2(x) exp2f(x)
#endif

static __device__ __forceinline__ ushort f2bf(float f) {
    __hip_bfloat16 h = __float2bfloat16(f);
    return __builtin_bit_cast(ushort, h);
}

// K1: WhT[f][row] = bf16(x @ W); Wh1/Wh2 = (Wh @ a) * log2e  (fp32)
// grid NN/16 = 512 blocks x 256 thr (2/CU). Wave: 4 rows. W values loaded once
// per k-step and reused across the 4 rows (VMEM ~128/thread, was ~2048).
// x loads are wave-uniform (readfirstlane on wave id) -> scalar loads.
__global__ __launch_bounds__(256) void gat_proj(const float* __restrict__ x,
                                                const float* __restrict__ W,
                                                const float* __restrict__ a,
                                                ushort* __restrict__ WhT,
                                                float* __restrict__ Wh1,
                                                float* __restrict__ Wh2) {
    __shared__ float tile[16][FOUT + 1];

    const int t = threadIdx.x;
    const int f = t & 63;
    const int wvu = __builtin_amdgcn_readfirstlane(t >> 6);
    const int row0 = blockIdx.x * 16;
    const float af1 = a[f], af2 = a[FOUT + f];

    const float* __restrict__ xr = x + (size_t)(row0 + wvu * 4) * FIN;

    float accv[4] = {0.f, 0.f, 0.f, 0.f};
    #pragma unroll
    for (int k = 0; k < FIN; k += 4) {
        const float w0 = W[(k + 0) * FOUT + f];
        const float w1 = W[(k + 1) * FOUT + f];
        const float w2 = W[(k + 2) * FOUT + f];
        const float w3 = W[(k + 3) * FOUT + f];
        #pragma unroll
        for (int r = 0; r < 4; ++r) {
            const float4 xv = *(const float4*)(xr + (size_t)r * FIN + k);
            accv[r] = fmaf(xv.x, w0, fmaf(xv.y, w1, fmaf(xv.z, w2, fmaf(xv.w, w3, accv[r]))));
        }
    }

    #pragma unroll
    for (int r = 0; r < 4; ++r) {
        tile[wvu * 4 + r][f] = accv[r];
        float s1 = accv[r] * af1;
        float s2 = accv[r] * af2;
        #pragma unroll
        for (int off = 32; off; off >>= 1) {
            s1 += __shfl_xor(s1, off, 64);
            s2 += __shfl_xor(s2, off, 64);
        }
        if (f == 0) {
            const int row = row0 + wvu * 4 + r;
            Wh1[row] = s1 * LOG2E;      // pre-fold log2e: leaky is +scale-invariant
            Wh2[row] = s2 * LOG2E;
        }
    }
    __syncthreads();

    // transpose out: lanes r=t&15 write 2B consecutive (32B runs per f).
    // tile read stride 65 dwords -> bank = r*65+ff mod 32, conflict-free.
    const int r = t & 15;
    const int fh = t >> 4;     // 0..15
    #pragma unroll
    for (int p = 0; p < 4; ++p) {
        const int ff = p * 16 + fh;
        WhT[(size_t)ff * NN + row0 + r] = f2bf(tile[r][ff]);
    }
}

// K2: partial masked-softmax num/den via bf16 MFMA, 2-deep SW pipeline.
// grid (NN/BM)*SPLIT = 1024 blocks x 256 thr (4 waves).
// Iter c: issue adj(c+2) | MFMA(c) | issue B(c+2) | scores(c+1)->LDS | sync.
// adj(c+1) was issued one full iteration earlier -> ~2 phases of latency slack.
__global__ __launch_bounds__(256) void gat_attn_part(const int* __restrict__ adj,
                                                     const ushort* __restrict__ WhT,
                                                     const float* __restrict__ Wh1,
                                                     const float* __restrict__ Wh2,
                                                     float* __restrict__ pnum,
                                                     float* __restrict__ pden) {
    __shared__ __align__(16) ushort P[2][BM][PROW];   // 34.8 KB

    const int t = threadIdx.x;
    const int lane = t & 63;
    const int wvu = __builtin_amdgcn_readfirstlane(t >> 6);
    const int slice = blockIdx.x & (SPLIT - 1);
    const int row0 = (blockIdx.x / SPLIT) * BM;
    const int j0 = slice * JSLICE;
    const int ln = lane & 15;
    const int quad = lane >> 4;
    const int jg = lane & 31;      // j-group within chunk (4 j each)
    const int rh = lane >> 5;      // row half (0/1) within wave's 16 rows
    const int rbase = wvu * 16;

    float wh1r[8];
    #pragma unroll
    for (int rr = 0; rr < 8; ++rr)
        wh1r[rr] = Wh1[row0 + rbase + rh * 8 + rr];

    const int* __restrict__ aptr =
        adj + (size_t)(row0 + rbase + rh * 8) * NN + j0 + jg * 4;
    const ushort* __restrict__ bbase =
        WhT + (size_t)(wvu * 16 + ln) * NN + j0 + quad * 8;

    int4 avb[2][8];
    float4 wh2b[2];
    short8 bfb[2][4];
    float den[8];
    #pragma unroll
    for (int rr = 0; rr < 8; ++rr) den[rr] = 0.f;
    floatx4 acc[4];
    #pragma unroll
    for (int mt = 0; mt < 4; ++mt) acc[mt] = (floatx4){0.f, 0.f, 0.f, 0.f};

    auto loadAdj = [&](int c, int s) {
        const int jb = c * CHUNK;
        wh2b[s] = *(const float4*)(Wh2 + j0 + jb + jg * 4);
        #pragma unroll
        for (int rr = 0; rr < 8; ++rr)
            avb[s][rr] = *(const int4*)(aptr + (size_t)rr * NN + jb);
    };
    auto loadB = [&](int c, int s) {
        #pragma unroll
        for (int k0 = 0; k0 < 4; ++k0)
            bfb[s][k0] = *(const short8*)(bbase + c * CHUNK + k0 * 32);
    };
    auto scores = [&](int s, int b) {
        #pragma unroll
        for (int rr = 0; rr < 8; ++rr) {
            const float w1 = wh1r[rr];
            float s0 = w1 + wh2b[s].x, s1 = w1 + wh2b[s].y,
                  s2 = w1 + wh2b[s].z, s3 = w1 + wh2b[s].w;
            s0 = fmaxf(s0, ALPHA * s0); s1 = fmaxf(s1, ALPHA * s1);
            s2 = fmaxf(s2, ALPHA * s2); s3 = fmaxf(s3, ALPHA * s3);
            float p0 = EXP2(s0), p1 = EXP2(s1), p2 = EXP2(s2), p3 = EXP2(s3);
            p0 = (avb[s][rr].x > 0) ? p0 : 0.f;
            p1 = (avb[s][rr].y > 0) ? p1 : 0.f;
            p2 = (avb[s][rr].z > 0) ? p2 : 0.f;
            p3 = (avb[s][rr].w > 0) ? p3 : 0.f;
            den[rr] += (p0 + p1) + (p2 + p3);
            ushort4 pk = make_ushort4(f2bf(p0), f2bf(p1), f2bf(p2), f2bf(p3));
            *(ushort4*)&P[b][rbase + rh * 8 + rr][jg * 4] = pk;
        }
    };

    loadAdj(0, 0); loadB(0, 0);
    loadAdj(1, 1); loadB(1, 1);
    scores(0, 0);
    __syncthreads();

    int pb = 0;
    for (int c = 0; c < NCHUNK; ++c) {
        const int sc = c & 1;                       // stage holding chunk c's B
        if (c + 2 < NCHUNK) loadAdj(c + 2, sc);     // avb[sc] was consumed at c-1

        #pragma unroll
        for (int mt = 0; mt < 4; ++mt) {
            const ushort* Arow = &P[pb][mt * 16 + ln][quad * 8];
            #pragma unroll
            for (int k0 = 0; k0 < 4; ++k0) {
                short8 af = *(const short8*)(Arow + k0 * 32);
                acc[mt] = __builtin_amdgcn_mfma_f32_16x16x32_bf16(af, bfb[sc][k0], acc[mt], 0, 0, 0);
            }
        }
        if (c + 2 < NCHUNK) loadB(c + 2, sc);       // bfb[sc] just consumed
        if (c + 1 < NCHUNK) scores(sc ^ 1, pb ^ 1); // adj(c+1) loaded one iter ago
        __syncthreads();
        pb ^= 1;
    }

    // partial den: reduce across the 32-lane half (lanes of one rh share rows)
    #pragma unroll
    for (int rr = 0; rr < 8; ++rr) {
        float d = den[rr];
        #pragma unroll
        for (int off = 16; off; off >>= 1) d += __shfl_xor(d, off, 64);
        if (jg == 0)
            pden[(size_t)slice * NN + row0 + rbase + rh * 8 + rr] = d;
    }

    // partial num: D[m = quad*4 + r][n = ln] per m-tile (verified C/D layout)
    #pragma unroll
    for (int mt = 0; mt < 4; ++mt) {
        #pragma unroll
        for (int r = 0; r < 4; ++r) {
            const int i = mt * 16 + quad * 4 + r;
            pnum[((size_t)slice * NN + row0 + i) * FOUT + wvu * 16 + ln] = acc[mt][r];
        }
    }
}

// K3: combine SPLIT partials, normalize, ELU. grid NN*FOUT/256.
__global__ __launch_bounds__(256) void gat_combine(const float* __restrict__ pnum,
                                                   const float* __restrict__ pden,
                                                   float* __restrict__ out) {
    const int idx = blockIdx.x * 256 + threadIdx.x;
    const int row = idx >> 6;
    float num = 0.f, den = 0.f;
    #pragma unroll
    for (int s = 0; s < SPLIT; ++s) {
        num += pnum[(size_t)s * NN * FOUT + idx];
        den += pden[(size_t)s * NN + row];
    }
    float o = num / den;
    o = (o > 0.f) ? o : (__expf(o) - 1.f);
    out[idx] = o;
}

extern "C" void kernel_launch(void* const* d_in, const int* in_sizes, int n_in,
                              void* d_out, int out_size, void* d_ws, size_t ws_size,
                              hipStream_t stream) {
    const float* x   = (const float*)d_in[0];   // [N, FIN]
    const int*   adj = (const int*)  d_in[1];   // [N, N]
    const float* W   = (const float*)d_in[2];   // [FIN, FOUT]
    const float* a   = (const float*)d_in[3];   // [2*FOUT, 1]
    float* out = (float*)d_out;                 // [N, FOUT]

    // ws: WhT bf16 [64][8192] (1MB) | Wh1 f32 [N] | Wh2 f32 [N]
    //   | pnum f32 [SPLIT][N][FOUT] (16MB) | pden f32 [SPLIT][N] (256KB)
    ushort* WhT = (ushort*)d_ws;
    float* Wh1 = (float*)(WhT + (size_t)FOUT * NN);
    float* Wh2 = Wh1 + NN;
    float* pnum = Wh2 + NN;
    float* pden = pnum + (size_t)SPLIT * NN * FOUT;

    gat_proj<<<NN / 16, 256, 0, stream>>>(x, W, a, WhT, Wh1, Wh2);
    gat_attn_part<<<(NN / BM) * SPLIT, 256, 0, stream>>>(adj, WhT, Wh1, Wh2, pnum, pden);
    gat_combine<<<NN * FOUT / 256, 256, 0, stream>>>(pnum, pden, out);
}

// Round 6
// 440.750 us; speedup vs baseline: 2.4714x; 2.4714x over previous
//
#include <hip/hip_runtime.h>
#include <hip/hip_bf16.h>

#define NN 8192
#define FIN 128
#define FOUT 64
#define ALPHA 0.2f
#define BM 64                // rows per attn block
#define CHUNK 128            // j-tile per pipeline stage
#define SPLIT 8              // j-range split factor (1024 j per block)
#define JSLICE (NN / SPLIT)
#define NCHUNK (JSLICE / CHUNK)   // 8
#define PROW (CHUNK + 8)     // 272B row stride: 4-bank skew
#define LOG2E 1.44269504f
#define MROW (NN / 32)       // uint32 mask words per row (256)

typedef __attribute__((ext_vector_type(8))) short short8;   // 8 bf16 (4 VGPRs)
typedef __attribute__((ext_vector_type(4))) float floatx4;

#if __has_builtin(__builtin_amdgcn_exp2f)
#define EXP2(x) __builtin_amdgcn_exp2f(x)
#else
#define EXP2(x) exp2f(x)
#endif

static __device__ __forceinline__ ushort f2bf(float f) {
    __hip_bfloat16 h = __float2bfloat16(f);
    return __builtin_bit_cast(ushort, h);
}

// K0: adj int32 -> 1-bit mask. Pure stream: 268MB read, 8.4MB write.
// 8192 blocks x 256 thr; block = one row; wave wv covers words wv*32..+31.
// ballot bit l = adj[row][k*64+l] > 0  (uint64 word k).
__global__ __launch_bounds__(256) void adj_to_mask(const int* __restrict__ adj,
                                                   unsigned long long* __restrict__ mask) {
    const int t = threadIdx.x;
    const int lane = t & 63;
    const int wv = t >> 6;
    const int row = blockIdx.x;
    const int* __restrict__ ap = adj + (size_t)row * NN + lane;
    unsigned long long* __restrict__ mp = mask + (size_t)row * (NN / 64);
    #pragma unroll 2
    for (int i = 0; i < 8; ++i) {
        const int k = wv * 32 + i * 4;
        const int a0 = ap[(size_t)(k + 0) * 64];
        const int a1 = ap[(size_t)(k + 1) * 64];
        const int a2 = ap[(size_t)(k + 2) * 64];
        const int a3 = ap[(size_t)(k + 3) * 64];
        const unsigned long long m0 = __ballot(a0 > 0);
        const unsigned long long m1 = __ballot(a1 > 0);
        const unsigned long long m2 = __ballot(a2 > 0);
        const unsigned long long m3 = __ballot(a3 > 0);
        if (lane == 0) {
            mp[k + 0] = m0; mp[k + 1] = m1; mp[k + 2] = m2; mp[k + 3] = m3;
        }
    }
}

// K1: WhT[f][row] = bf16(x @ W); Wh1/Wh2 = (Wh @ a) * log2e  (fp32)
// grid NN/16 = 512 blocks x 256 thr. Wave: 4 rows, W reused across rows.
__global__ __launch_bounds__(256) void gat_proj(const float* __restrict__ x,
                                                const float* __restrict__ W,
                                                const float* __restrict__ a,
                                                ushort* __restrict__ WhT,
                                                float* __restrict__ Wh1,
                                                float* __restrict__ Wh2) {
    __shared__ float tile[16][FOUT + 1];

    const int t = threadIdx.x;
    const int f = t & 63;
    const int wvu = __builtin_amdgcn_readfirstlane(t >> 6);
    const int row0 = blockIdx.x * 16;
    const float af1 = a[f], af2 = a[FOUT + f];

    const float* __restrict__ xr = x + (size_t)(row0 + wvu * 4) * FIN;

    float accv[4] = {0.f, 0.f, 0.f, 0.f};
    #pragma unroll
    for (int k = 0; k < FIN; k += 4) {
        const float w0 = W[(k + 0) * FOUT + f];
        const float w1 = W[(k + 1) * FOUT + f];
        const float w2 = W[(k + 2) * FOUT + f];
        const float w3 = W[(k + 3) * FOUT + f];
        #pragma unroll
        for (int r = 0; r < 4; ++r) {
            const float4 xv = *(const float4*)(xr + (size_t)r * FIN + k);
            accv[r] = fmaf(xv.x, w0, fmaf(xv.y, w1, fmaf(xv.z, w2, fmaf(xv.w, w3, accv[r]))));
        }
    }

    #pragma unroll
    for (int r = 0; r < 4; ++r) {
        tile[wvu * 4 + r][f] = accv[r];
        float s1 = accv[r] * af1;
        float s2 = accv[r] * af2;
        #pragma unroll
        for (int off = 32; off; off >>= 1) {
            s1 += __shfl_xor(s1, off, 64);
            s2 += __shfl_xor(s2, off, 64);
        }
        if (f == 0) {
            const int row = row0 + wvu * 4 + r;
            Wh1[row] = s1 * LOG2E;      // pre-fold log2e: leaky is +scale-invariant
            Wh2[row] = s2 * LOG2E;
        }
    }
    __syncthreads();

    const int r = t & 15;
    const int fh = t >> 4;
    #pragma unroll
    for (int p = 0; p < 4; ++p) {
        const int ff = p * 16 + fh;
        WhT[(size_t)ff * NN + row0 + r] = f2bf(tile[r][ff]);
    }
}

// K2: partial masked-softmax num/den via bf16 MFMA, mask-bit input.
// grid (NN/BM)*SPLIT = 1024 blocks x 256 thr (4 waves), ~4 blocks/CU.
// Statically-unrolled even/odd 2-deep pipeline (NO dynamic reg indexing).
__global__ __launch_bounds__(256) void gat_attn_part(const unsigned int* __restrict__ mask32,
                                                     const ushort* __restrict__ WhT,
                                                     const float* __restrict__ Wh1,
                                                     const float* __restrict__ Wh2,
                                                     float* __restrict__ pnum,
                                                     float* __restrict__ pden) {
    __shared__ __align__(16) ushort P[2][BM][PROW];   // 34.8 KB

    const int t = threadIdx.x;
    const int lane = t & 63;
    const int wvu = __builtin_amdgcn_readfirstlane(t >> 6);
    const int slice = blockIdx.x & (SPLIT - 1);
    const int row0 = (blockIdx.x / SPLIT) * BM;
    const int j0 = slice * JSLICE;
    const int ln = lane & 15;
    const int quad = lane >> 4;
    const int jg = lane & 31;      // j-group within chunk (4 j each)
    const int rh = lane >> 5;      // row half (0/1) of wave's 16 score rows
    const int rbase = wvu * 16;
    const int sh = (jg & 7) * 4;   // bit offset of this lane's 4 mask bits

    float wh1r[8];
    #pragma unroll
    for (int rr = 0; rr < 8; ++rr)
        wh1r[rr] = Wh1[row0 + rbase + rh * 8 + rr];

    // mask base: lane reads word (j0+jb)/32 + jg/8 of its row
    const unsigned int* __restrict__ mrowp =
        mask32 + (size_t)(row0 + rbase + rh * 8) * MROW + j0 / 32 + (jg >> 3);
    const ushort* __restrict__ bbase =
        WhT + (size_t)(wvu * 16 + ln) * NN + j0 + quad * 8;

    unsigned int mE[8], mO[8];
    float4 wh2E, wh2O;
    short8 bfE[4], bfO[4];
    float den[8];
    #pragma unroll
    for (int rr = 0; rr < 8; ++rr) den[rr] = 0.f;
    floatx4 acc[4];
    #pragma unroll
    for (int mt = 0; mt < 4; ++mt) acc[mt] = (floatx4){0.f, 0.f, 0.f, 0.f};

#define LOADM(c, M, WH2)                                                   \
    {                                                                      \
        WH2 = *(const float4*)(Wh2 + j0 + (c) * CHUNK + jg * 4);           \
        _Pragma("unroll")                                                  \
        for (int rr = 0; rr < 8; ++rr)                                     \
            M[rr] = mrowp[(size_t)rr * MROW + (c) * (CHUNK / 32)];         \
    }
#define LOADB(c, BF)                                                       \
    {                                                                      \
        _Pragma("unroll")                                                  \
        for (int k0 = 0; k0 < 4; ++k0)                                     \
            BF[k0] = *(const short8*)(bbase + (c) * CHUNK + k0 * 32);      \
    }
#define SCORES(M, WH2, b)                                                  \
    {                                                                      \
        _Pragma("unroll")                                                  \
        for (int rr = 0; rr < 8; ++rr) {                                   \
            const float w1 = wh1r[rr];                                     \
            float s0 = w1 + WH2.x, s1 = w1 + WH2.y,                        \
                  s2 = w1 + WH2.z, s3 = w1 + WH2.w;                        \
            s0 = fmaxf(s0, ALPHA * s0); s1 = fmaxf(s1, ALPHA * s1);        \
            s2 = fmaxf(s2, ALPHA * s2); s3 = fmaxf(s3, ALPHA * s3);        \
            float p0 = EXP2(s0), p1 = EXP2(s1),                            \
                  p2 = EXP2(s2), p3 = EXP2(s3);                            \
            const unsigned int mm = M[rr];                                 \
            p0 = (mm & (1u << (sh + 0))) ? p0 : 0.f;                       \
            p1 = (mm & (1u << (sh + 1))) ? p1 : 0.f;                       \
            p2 = (mm & (1u << (sh + 2))) ? p2 : 0.f;                       \
            p3 = (mm & (1u << (sh + 3))) ? p3 : 0.f;                       \
            den[rr] += (p0 + p1) + (p2 + p3);                              \
            ushort4 pk = make_ushort4(f2bf(p0), f2bf(p1), f2bf(p2), f2bf(p3)); \
            *(ushort4*)&P[b][rbase + rh * 8 + rr][jg * 4] = pk;            \
        }                                                                  \
    }
#define MFMA(b, BF)                                                        \
    {                                                                      \
        _Pragma("unroll")                                                  \
        for (int mt = 0; mt < 4; ++mt) {                                   \
            const ushort* Arow = &P[b][mt * 16 + ln][quad * 8];            \
            _Pragma("unroll")                                              \
            for (int k0 = 0; k0 < 4; ++k0) {                               \
                short8 af = *(const short8*)(Arow + k0 * 32);              \
                acc[mt] = __builtin_amdgcn_mfma_f32_16x16x32_bf16(af, BF[k0], acc[mt], 0, 0, 0); \
            }                                                              \
        }                                                                  \
    }

    // prologue
    LOADM(0, mE, wh2E); LOADB(0, bfE);
    LOADM(1, mO, wh2O); LOADB(1, bfO);
    SCORES(mE, wh2E, 0);          // chunk 0 -> buf0 (consumes E)
    LOADM(2, mE, wh2E);           // refill E
    __syncthreads();

    #pragma unroll
    for (int c = 0; c < NCHUNK; c += 2) {
        // even chunk c: MFMA from buf0 with bfE
        MFMA(0, bfE);
        if (c + 2 < NCHUNK) LOADB(c + 2, bfE);
        SCORES(mO, wh2O, 1);                       // chunk c+1 -> buf1
        if (c + 3 < NCHUNK) LOADM(c + 3, mO, wh2O);
        __syncthreads();
        // odd chunk c+1: MFMA from buf1 with bfO
        MFMA(1, bfO);
        if (c + 3 < NCHUNK) LOADB(c + 3, bfO);
        if (c + 2 < NCHUNK) SCORES(mE, wh2E, 0);   // chunk c+2 -> buf0
        if (c + 4 < NCHUNK) LOADM(c + 4, mE, wh2E);
        __syncthreads();
    }
#undef LOADM
#undef LOADB
#undef SCORES
#undef MFMA

    // partial den: reduce across the 32-lane half (lanes of one rh share rows)
    #pragma unroll
    for (int rr = 0; rr < 8; ++rr) {
        float d = den[rr];
        #pragma unroll
        for (int off = 16; off; off >>= 1) d += __shfl_xor(d, off, 64);
        if (jg == 0)
            pden[(size_t)slice * NN + row0 + rbase + rh * 8 + rr] = d;
    }

    // partial num: D[m = quad*4 + r][n = ln] per m-tile (verified C/D layout)
    #pragma unroll
    for (int mt = 0; mt < 4; ++mt) {
        #pragma unroll
        for (int r = 0; r < 4; ++r) {
            const int i = mt * 16 + quad * 4 + r;
            pnum[((size_t)slice * NN + row0 + i) * FOUT + wvu * 16 + ln] = acc[mt][r];
        }
    }
}

// K3: combine SPLIT partials, normalize, ELU. grid NN*FOUT/256.
__global__ __launch_bounds__(256) void gat_combine(const float* __restrict__ pnum,
                                                   const float* __restrict__ pden,
                                                   float* __restrict__ out) {
    const int idx = blockIdx.x * 256 + threadIdx.x;
    const int row = idx >> 6;
    float num = 0.f, den = 0.f;
    #pragma unroll
    for (int s = 0; s < SPLIT; ++s) {
        num += pnum[(size_t)s * NN * FOUT + idx];
        den += pden[(size_t)s * NN + row];
    }
    float o = num / den;
    o = (o > 0.f) ? o : (__expf(o) - 1.f);
    out[idx] = o;
}

extern "C" void kernel_launch(void* const* d_in, const int* in_sizes, int n_in,
                              void* d_out, int out_size, void* d_ws, size_t ws_size,
                              hipStream_t stream) {
    const float* x   = (const float*)d_in[0];   // [N, FIN]
    const int*   adj = (const int*)  d_in[1];   // [N, N]
    const float* W   = (const float*)d_in[2];   // [FIN, FOUT]
    const float* a   = (const float*)d_in[3];   // [2*FOUT, 1]
    float* out = (float*)d_out;                 // [N, FOUT]

    // ws: WhT bf16 [64][8192] (1MB) | Wh1 f32 [N] | Wh2 f32 [N]
    //   | pnum f32 [SPLIT][N][FOUT] (16MB) | pden f32 [SPLIT][N] (256KB)
    //   | mask u64 [N][N/64] (8.4MB)
    ushort* WhT = (ushort*)d_ws;
    float* Wh1 = (float*)(WhT + (size_t)FOUT * NN);
    float* Wh2 = Wh1 + NN;
    float* pnum = Wh2 + NN;
    float* pden = pnum + (size_t)SPLIT * NN * FOUT;
    unsigned long long* mask = (unsigned long long*)(pden + (size_t)SPLIT * NN);

    adj_to_mask<<<NN, 256, 0, stream>>>(adj, mask);
    gat_proj<<<NN / 16, 256, 0, stream>>>(x, W, a, WhT, Wh1, Wh2);
    gat_attn_part<<<(NN / BM) * SPLIT, 256, 0, stream>>>((const unsigned int*)mask,
                                                         WhT, Wh1, Wh2, pnum, pden);
    gat_combine<<<NN * FOUT / 256, 256, 0, stream>>>(pnum, pden, out);
}